// Round 1
// baseline (121.255 us; speedup 1.0000x reference)
//
#include <hip/hip_runtime.h>

#define TLEN 512
#define LOG2E 1.44269504088896340736f

#if __has_builtin(__builtin_amdgcn_exp2f)
#define EXP2F(x) __builtin_amdgcn_exp2f(x)
#else
#define EXP2F(x) __exp2f(x)
#endif
#if __has_builtin(__builtin_amdgcn_rcpf)
#define RCPF(x) __builtin_amdgcn_rcpf(x)
#else
#define RCPF(x) (1.0f / (x))
#endif

// ds_swizzle BitMode: lane reads from ((lane & 0x1F) | 0) ^ xm  — XOR is symmetric, no direction ambiguity
#define SWZ(v, xm) __int_as_float(__builtin_amdgcn_ds_swizzle(__float_as_int(v), (((xm) << 10) | 0x1F)))
// DPP quad_perm broadcast of quad-lane k to all 4 lanes of each quad (VALU-rate)
#define QB(v, k) __int_as_float(__builtin_amdgcn_update_dpp(__float_as_int(v), __float_as_int(v), 0x55 * (k), 0xF, 0xF, false))

__global__ __launch_bounds__(256, 1) void lstm_mlp_kernel(
    const float* __restrict__ x,   // [B,512,16]
    const float* __restrict__ Wk,  // [16,16]
    const float* __restrict__ Wr,  // [4,16]
    const float* __restrict__ bg,  // [16]
    const float* __restrict__ W1,  // [4,64]
    const float* __restrict__ b1,  // [64]
    const float* __restrict__ W2,  // [64,5]
    const float* __restrict__ b2,  // [5]
    float* __restrict__ out,       // [B,5]
    int B)
{
    const int tid = blockIdx.x * 256 + threadIdx.x;
    const int seq = tid >> 4;
    if (seq >= B) return;
    const int i16 = tid & 15;
    const int j   = i16 >> 2;   // hidden unit owned by this quad
    const int q   = i16 & 3;    // gate type: 0=i, 1=f, 2=g(tanh), 3=o
    const int gate = q * 4 + j; // column in gates[16] (order i,f,g,o)

    // per-lane weights in VGPRs
    float wk[16];
#pragma unroll
    for (int f = 0; f < 16; ++f) wk[f] = Wk[f * 16 + gate];
    const float wr0 = Wr[(j ^ 0) * 16 + gate];
    const float wr1 = Wr[(j ^ 1) * 16 + gate];
    const float wr2 = Wr[(j ^ 2) * 16 + gate];
    const float wr3 = Wr[(j ^ 3) * 16 + gate];
    const float bias = bg[gate];

    // branchless activation: av = m1 * rcp(1 + exp2(k1*x)) + m0
    // sigmoid: k1=-log2e, m1=1, m0=0 ; tanh: k1=-2log2e, m1=2, m0=-1
    const bool is_tanh = (q == 2);
    const float k1 = is_tanh ? (-2.0f * LOG2E) : (-LOG2E);
    const float m1 = is_tanh ? 2.0f : 1.0f;
    const float m0 = is_tanh ? -1.0f : 0.0f;

    const float4* xq = reinterpret_cast<const float4*>(x) + (size_t)seq * (TLEN * 4);

    float c = 0.0f, h = 0.0f;

#define DOT16(R0, R1, R2, R3) ( \
    (fmaf((R0).x, wk[0], fmaf((R0).y, wk[1], fmaf((R0).z, wk[2], (R0).w * wk[3]))) + \
     fmaf((R1).x, wk[4], fmaf((R1).y, wk[5], fmaf((R1).z, wk[6], (R1).w * wk[7])))) + \
    (fmaf((R2).x, wk[8], fmaf((R2).y, wk[9], fmaf((R2).z, wk[10], (R2).w * wk[11]))) + \
     fmaf((R3).x, wk[12], fmaf((R3).y, wk[13], fmaf((R3).z, wk[14], (R3).w * wk[15])))) )

#define STEP(XD) { \
    float hB_ = SWZ(h, 4);  /* h[j^1] */ \
    float hC_ = SWZ(h, 8);  /* h[j^2] */ \
    float hD_ = SWZ(h, 12); /* h[j^3] */ \
    float pre = fmaf(h, wr0, (XD)); \
    pre = fmaf(hB_, wr1, pre); \
    pre = fmaf(hC_, wr2, pre); \
    pre = fmaf(hD_, wr3, pre); \
    float r_ = RCPF(1.0f + EXP2F(k1 * pre)); \
    float av = fmaf(m1, r_, m0); \
    float iv = QB(av, 0); \
    float fv = QB(av, 1); \
    float gv = QB(av, 2); \
    float ov = QB(av, 3); \
    c = fmaf(fv, c, iv * gv); \
    float th_ = fmaf(2.0f, RCPF(1.0f + EXP2F(-2.0f * LOG2E * c)), -1.0f); \
    h = ov * th_; }

    // 4-deep prefetch pipeline: buffers A,B,C,D hold x(t)..x(t+3)
    float4 A0 = xq[0],  A1 = xq[1],  A2 = xq[2],  A3 = xq[3];
    float4 B0 = xq[4],  B1 = xq[5],  B2 = xq[6],  B3 = xq[7];
    float4 C0 = xq[8],  C1 = xq[9],  C2 = xq[10], C3 = xq[11];
    float4 D0 = xq[12], D1 = xq[13], D2 = xq[14], D3 = xq[15];

    float xd = DOT16(A0, A1, A2, A3) + bias; // t = 0

    for (int t = 0; t < TLEN; t += 4) {
        int t4 = t + 4 < TLEN ? t + 4 : TLEN - 1;
        A0 = xq[t4*4+0]; A1 = xq[t4*4+1]; A2 = xq[t4*4+2]; A3 = xq[t4*4+3];
        float xdB = DOT16(B0, B1, B2, B3) + bias;
        STEP(xd);            // t
        int t5 = t + 5 < TLEN ? t + 5 : TLEN - 1;
        B0 = xq[t5*4+0]; B1 = xq[t5*4+1]; B2 = xq[t5*4+2]; B3 = xq[t5*4+3];
        float xdC = DOT16(C0, C1, C2, C3) + bias;
        STEP(xdB);           // t+1
        int t6 = t + 6 < TLEN ? t + 6 : TLEN - 1;
        C0 = xq[t6*4+0]; C1 = xq[t6*4+1]; C2 = xq[t6*4+2]; C3 = xq[t6*4+3];
        float xdD = DOT16(D0, D1, D2, D3) + bias;
        STEP(xdC);           // t+2
        int t7 = t + 7 < TLEN ? t + 7 : TLEN - 1;
        D0 = xq[t7*4+0]; D1 = xq[t7*4+1]; D2 = xq[t7*4+2]; D3 = xq[t7*4+3];
        xd = DOT16(A0, A1, A2, A3) + bias;   // for t+4
        STEP(xdD);           // t+3
    }

    // ---- MLP head ----
    float hA = h;
    float hB = SWZ(h, 4), hC = SWZ(h, 8), hD = SWZ(h, 12);

    float p0 = 0.f, p1 = 0.f, p2 = 0.f, p3 = 0.f, p4 = 0.f;
#pragma unroll
    for (int r = 0; r < 4; ++r) {
        const int u = i16 * 4 + r;            // hidden unit, 4 per lane
        float acc = b1[u];
        acc = fmaf(hA, W1[(j ^ 0) * 64 + u], acc);
        acc = fmaf(hB, W1[(j ^ 1) * 64 + u], acc);
        acc = fmaf(hC, W1[(j ^ 2) * 64 + u], acc);
        acc = fmaf(hD, W1[(j ^ 3) * 64 + u], acc);
        acc = fmaxf(acc, 0.0f);
        p0 = fmaf(acc, W2[u * 5 + 0], p0);
        p1 = fmaf(acc, W2[u * 5 + 1], p1);
        p2 = fmaf(acc, W2[u * 5 + 2], p2);
        p3 = fmaf(acc, W2[u * 5 + 3], p3);
        p4 = fmaf(acc, W2[u * 5 + 4], p4);
    }
    // butterfly all-reduce across the 16-lane group
    p0 += SWZ(p0, 1); p1 += SWZ(p1, 1); p2 += SWZ(p2, 1); p3 += SWZ(p3, 1); p4 += SWZ(p4, 1);
    p0 += SWZ(p0, 2); p1 += SWZ(p1, 2); p2 += SWZ(p2, 2); p3 += SWZ(p3, 2); p4 += SWZ(p4, 2);
    p0 += SWZ(p0, 4); p1 += SWZ(p1, 4); p2 += SWZ(p2, 4); p3 += SWZ(p3, 4); p4 += SWZ(p4, 4);
    p0 += SWZ(p0, 8); p1 += SWZ(p1, 8); p2 += SWZ(p2, 8); p3 += SWZ(p3, 8); p4 += SWZ(p4, 8);

    p0 += b2[0]; p1 += b2[1]; p2 += b2[2]; p3 += b2[3]; p4 += b2[4];

    float mx = fmaxf(fmaxf(fmaxf(p0, p1), fmaxf(p2, p3)), p4);
    float e0 = EXP2F((p0 - mx) * LOG2E);
    float e1 = EXP2F((p1 - mx) * LOG2E);
    float e2 = EXP2F((p2 - mx) * LOG2E);
    float e3 = EXP2F((p3 - mx) * LOG2E);
    float e4 = EXP2F((p4 - mx) * LOG2E);
    float s = ((e0 + e1) + (e2 + e3)) + e4;
    float rs = RCPF(s);

    if (i16 == 0) {
        float* op = out + (size_t)seq * 5;
        op[0] = e0 * rs; op[1] = e1 * rs; op[2] = e2 * rs;
        op[3] = e3 * rs; op[4] = e4 * rs;
    }
}

extern "C" void kernel_launch(void* const* d_in, const int* in_sizes, int n_in,
                              void* d_out, int out_size, void* d_ws, size_t ws_size,
                              hipStream_t stream) {
    const float* x  = (const float*)d_in[0];
    const float* Wk = (const float*)d_in[1];
    const float* Wr = (const float*)d_in[2];
    const float* bg = (const float*)d_in[3];
    const float* W1 = (const float*)d_in[4];
    const float* b1 = (const float*)d_in[5];
    const float* W2 = (const float*)d_in[6];
    const float* b2 = (const float*)d_in[7];
    float* out = (float*)d_out;

    const int B = in_sizes[0] / (TLEN * 16);   // 4096
    const int threads = B * 16;
    dim3 block(256);
    dim3 grid((threads + 255) / 256);
    lstm_mlp_kernel<<<grid, block, 0, stream>>>(x, Wk, Wr, bg, W1, b1, W2, b2, out, B);
}

// Round 2
// 73.539 us; speedup vs baseline: 1.6488x; 1.6488x over previous
//
#include <hip/hip_runtime.h>

#define TLEN 512
#define LOG2E 1.44269504088896340736f

#if __has_builtin(__builtin_amdgcn_exp2f)
#define EXP2F(x) __builtin_amdgcn_exp2f(x)
#else
#define EXP2F(x) __exp2f(x)
#endif
#if __has_builtin(__builtin_amdgcn_rcpf)
#define RCPF(x) __builtin_amdgcn_rcpf(x)
#else
#define RCPF(x) (1.0f / (x))
#endif

// ds_swizzle BitMode xor (used only in the epilogue MLP head, off the hot loop)
#define SWZ(v, xm) __int_as_float(__builtin_amdgcn_ds_swizzle(__float_as_int(v), (((xm) << 10) | 0x1F)))
// Generic DPP: dst = src[permuted lane], all lanes valid (row/bank masks full, no bound ctrl)
#define DPPF(v, ctrl) __int_as_float(__builtin_amdgcn_update_dpp(__float_as_int(v), __float_as_int(v), (ctrl), 0xF, 0xF, false))
// quad_perm broadcast of quad-lane k (verified passing in round 1)
#define QB(v, k) DPPF(v, 0x55 * (k))
// Direction-free lane exchanges within a row of 16:
//   lane^4  = ROW_HALF_MIRROR(quad_perm[3,2,1,0])  (xor7 ∘ xor3)
//   lane^8  = ROW_ROR:8   ((l±8)&15 == l^8 either way)
//   lane^12 = ROR8(lane^4)
#define XOR3(v)  DPPF(v, 0x1B)   // quad_perm [3,2,1,0]
#define XOR7(v)  DPPF(v, 0x141)  // ROW_HALF_MIRROR
#define XOR8(v)  DPPF(v, 0x128)  // ROW_ROR:8

struct X4 { float4 a, b, c, d; };   // one timestep: 16 floats, 64 B

__global__ __launch_bounds__(256, 1) void lstm_mlp_kernel(
    const float* __restrict__ x,   // [B,512,16]
    const float* __restrict__ Wk,  // [16,16]
    const float* __restrict__ Wr,  // [4,16]
    const float* __restrict__ bg,  // [16]
    const float* __restrict__ W1,  // [4,64]
    const float* __restrict__ b1,  // [64]
    const float* __restrict__ W2,  // [64,5]
    const float* __restrict__ b2,  // [5]
    float* __restrict__ out,       // [B,5]
    int B)
{
    const int tid = blockIdx.x * 256 + threadIdx.x;
    const int seq = tid >> 4;
    if (seq >= B) return;
    const int i16 = tid & 15;
    const int j   = i16 >> 2;   // hidden unit owned by this quad (lane bits 2-3)
    const int q   = i16 & 3;    // gate type (lane bits 0-1): 0=i, 1=f, 2=g(tanh), 3=o
    const int gate = q * 4 + j; // column in gates[16] (Keras order i,f,g,o)

    // Pre-scale: activation argument scale k1 folded into ALL weights + bias.
    // sigmoid lanes: k1 = -log2e  -> exp2(pre) = e^-raw -> r = sigmoid(raw), av = r
    // g lane:        k1 = -2log2e -> r = 1/(1+e^-2raw), tanh = 2r-1; broadcast K*tanh
    //                with K = -2log2e (cell kept in scaled form cs = K*c):
    //                av = 2K*r - K  (m1 = -4log2e, m0 = +2log2e)
    const bool is_g = (q == 2);
    const float k1 = is_g ? (-2.0f * LOG2E) : (-LOG2E);
    const float m1c = is_g ? (-4.0f * LOG2E) : 1.0f;
    const float m0c = is_g ? (2.0f * LOG2E) : 0.0f;

    float wk[16];
#pragma unroll
    for (int f = 0; f < 16; ++f) wk[f] = k1 * Wk[f * 16 + gate];
    const float wr0 = k1 * Wr[(j ^ 0) * 16 + gate];
    const float wr1 = k1 * Wr[(j ^ 1) * 16 + gate];
    const float wr2 = k1 * Wr[(j ^ 2) * 16 + gate];
    const float wr3 = k1 * Wr[(j ^ 3) * 16 + gate];
    const float biasS = k1 * bg[gate];

    const X4* xt = reinterpret_cast<const X4*>(x) + (size_t)seq * TLEN;

    float cs = 0.0f, h = 0.0f;   // cs = -2*log2e * c

#define DOT4S(v, w0_, w1_, w2_, w3_, seed) \
    fmaf((v).x, (w0_), fmaf((v).y, (w1_), fmaf((v).z, (w2_), fmaf((v).w, (w3_), (seed)))))
#define DOTB(Bk) \
    ((DOT4S((Bk).a, wk[0], wk[1], wk[2], wk[3], biasS) + \
      DOT4S((Bk).b, wk[4], wk[5], wk[6], wk[7], 0.0f)) + \
     (DOT4S((Bk).c, wk[8], wk[9], wk[10], wk[11], 0.0f) + \
      DOT4S((Bk).d, wk[12], wk[13], wk[14], wk[15], 0.0f)))

#define STEP(XD) { \
    float h1_ = XOR7(XOR3(h));   /* h[j^1] */ \
    float h2_ = XOR8(h);         /* h[j^2] */ \
    float h3_ = XOR8(h1_);       /* h[j^3] */ \
    float pre = fmaf(h, wr0, (XD)); \
    pre = fmaf(h2_, wr2, pre); \
    pre = fmaf(h1_, wr1, pre); \
    pre = fmaf(h3_, wr3, pre); \
    float r_ = RCPF(1.0f + EXP2F(pre)); \
    float av = fmaf(m1c, r_, m0c); \
    float iv = QB(av, 0); \
    float fv = QB(av, 1); \
    float gv = QB(av, 2); \
    float ov = QB(av, 3); \
    cs = fmaf(fv, cs, iv * gv); \
    float th_ = fmaf(2.0f, RCPF(1.0f + EXP2F(cs)), -1.0f); \
    h = ov * th_; }

    // 8-deep prefetch ring: B0..B7 hold x[t..t+7]; loads issued 8 steps ahead.
    X4 B0 = xt[0], B1 = xt[1], B2 = xt[2], B3 = xt[3];
    X4 B4 = xt[4], B5 = xt[5], B6 = xt[6], B7 = xt[7];

    for (int t = 0; t < TLEN - 8; t += 8) {
        { float xd = DOTB(B0); B0 = xt[t +  8]; STEP(xd); }
        { float xd = DOTB(B1); B1 = xt[t +  9]; STEP(xd); }
        { float xd = DOTB(B2); B2 = xt[t + 10]; STEP(xd); }
        { float xd = DOTB(B3); B3 = xt[t + 11]; STEP(xd); }
        { float xd = DOTB(B4); B4 = xt[t + 12]; STEP(xd); }
        { float xd = DOTB(B5); B5 = xt[t + 13]; STEP(xd); }
        { float xd = DOTB(B6); B6 = xt[t + 14]; STEP(xd); }
        { float xd = DOTB(B7); B7 = xt[t + 15]; STEP(xd); }
    }
    // tail: t = 504..511, no prefetch
    { float xd = DOTB(B0); STEP(xd); }
    { float xd = DOTB(B1); STEP(xd); }
    { float xd = DOTB(B2); STEP(xd); }
    { float xd = DOTB(B3); STEP(xd); }
    { float xd = DOTB(B4); STEP(xd); }
    { float xd = DOTB(B5); STEP(xd); }
    { float xd = DOTB(B6); STEP(xd); }
    { float xd = DOTB(B7); STEP(xd); }

    // ---- MLP head (runs once; ds_swizzle fine here) ----
    float hA = h;
    float hB = SWZ(h, 4), hC = SWZ(h, 8), hD = SWZ(h, 12);

    float p0 = 0.f, p1 = 0.f, p2 = 0.f, p3 = 0.f, p4 = 0.f;
#pragma unroll
    for (int r = 0; r < 4; ++r) {
        const int u = i16 * 4 + r;            // hidden unit of layer 1, 4 per lane
        float acc = b1[u];
        acc = fmaf(hA, W1[(j ^ 0) * 64 + u], acc);
        acc = fmaf(hB, W1[(j ^ 1) * 64 + u], acc);
        acc = fmaf(hC, W1[(j ^ 2) * 64 + u], acc);
        acc = fmaf(hD, W1[(j ^ 3) * 64 + u], acc);
        acc = fmaxf(acc, 0.0f);
        p0 = fmaf(acc, W2[u * 5 + 0], p0);
        p1 = fmaf(acc, W2[u * 5 + 1], p1);
        p2 = fmaf(acc, W2[u * 5 + 2], p2);
        p3 = fmaf(acc, W2[u * 5 + 3], p3);
        p4 = fmaf(acc, W2[u * 5 + 4], p4);
    }
    // butterfly all-reduce across the 16-lane group
    p0 += SWZ(p0, 1); p1 += SWZ(p1, 1); p2 += SWZ(p2, 1); p3 += SWZ(p3, 1); p4 += SWZ(p4, 1);
    p0 += SWZ(p0, 2); p1 += SWZ(p1, 2); p2 += SWZ(p2, 2); p3 += SWZ(p3, 2); p4 += SWZ(p4, 2);
    p0 += SWZ(p0, 4); p1 += SWZ(p1, 4); p2 += SWZ(p2, 4); p3 += SWZ(p3, 4); p4 += SWZ(p4, 4);
    p0 += SWZ(p0, 8); p1 += SWZ(p1, 8); p2 += SWZ(p2, 8); p3 += SWZ(p3, 8); p4 += SWZ(p4, 8);

    p0 += b2[0]; p1 += b2[1]; p2 += b2[2]; p3 += b2[3]; p4 += b2[4];

    float mx = fmaxf(fmaxf(fmaxf(p0, p1), fmaxf(p2, p3)), p4);
    float e0 = EXP2F((p0 - mx) * LOG2E);
    float e1 = EXP2F((p1 - mx) * LOG2E);
    float e2 = EXP2F((p2 - mx) * LOG2E);
    float e3 = EXP2F((p3 - mx) * LOG2E);
    float e4 = EXP2F((p4 - mx) * LOG2E);
    float s = ((e0 + e1) + (e2 + e3)) + e4;
    float rs = RCPF(s);

    if (i16 == 0) {
        float* op = out + (size_t)seq * 5;
        op[0] = e0 * rs; op[1] = e1 * rs; op[2] = e2 * rs;
        op[3] = e3 * rs; op[4] = e4 * rs;
    }
}

extern "C" void kernel_launch(void* const* d_in, const int* in_sizes, int n_in,
                              void* d_out, int out_size, void* d_ws, size_t ws_size,
                              hipStream_t stream) {
    const float* x  = (const float*)d_in[0];
    const float* Wk = (const float*)d_in[1];
    const float* Wr = (const float*)d_in[2];
    const float* bg = (const float*)d_in[3];
    const float* W1 = (const float*)d_in[4];
    const float* b1 = (const float*)d_in[5];
    const float* W2 = (const float*)d_in[6];
    const float* b2 = (const float*)d_in[7];
    float* out = (float*)d_out;

    const int B = in_sizes[0] / (TLEN * 16);   // 4096
    const int threads = B * 16;
    dim3 block(256);
    dim3 grid((threads + 255) / 256);
    lstm_mlp_kernel<<<grid, block, 0, stream>>>(x, Wk, Wr, bg, W1, b1, W2, b2, out, B);
}